// Round 4
// baseline (164.312 us; speedup 1.0000x reference)
//
#include <hip/hip_runtime.h>

typedef short bf16x8 __attribute__((ext_vector_type(8)));
typedef float f32x4 __attribute__((ext_vector_type(4)));

__device__ __forceinline__ unsigned short f2bf(float f) {
    unsigned int u = __float_as_uint(f);
    unsigned int r = u + 0x7FFFu + ((u >> 16) & 1u);
    return (unsigned short)(r >> 16);
}

// pack two f32 -> one u32 of 2 bf16 (lo = a, hi = b)
__device__ __forceinline__ unsigned pkbf(float a, float b) {
    unsigned r;
    asm volatile("v_cvt_pk_bf16_f32 %0, %1, %2" : "=v"(r) : "v"(a), "v"(b));
    return r;
}

// ---------------- weight prep: f32 row-major -> bf16 fragment-major ----------------
// frag layout: idx = ((nt*KS + ks)*64 + lane)*8 + e  ->  W[k = ks*32 + (lane>>4)*8 + e][n = nt*16 + (lane&15)]
__global__ __launch_bounds__(256) void prep_all(
        const float* __restrict__ uW1, const float* __restrict__ uW2, const float* __restrict__ uW3,
        const float* __restrict__ bW1, const float* __restrict__ bW2, const float* __restrict__ bW3,
        unsigned short* __restrict__ ws) {
    int idx = blockIdx.x * 256 + threadIdx.x;
    const float* W; int Ksrc, Nsrc, ntsh; unsigned short* dst; int li;
    if (idx < 8192)       { W = uW1; Ksrc = 38;  Nsrc = 128; ntsh = 10; dst = ws;         li = idx; }
    else if (idx < 16384) { W = bW1; Ksrc = 44;  Nsrc = 128; ntsh = 10; dst = ws + 8192;  li = idx - 8192; }
    else if (idx < 32768) { W = uW2; Ksrc = 128; Nsrc = 128; ntsh = 11; dst = ws + 16384; li = idx - 16384; }
    else if (idx < 49152) { W = bW2; Ksrc = 128; Nsrc = 128; ntsh = 11; dst = ws + 32768; li = idx - 32768; }
    else if (idx < 51200) { W = uW3; Ksrc = 128; Nsrc = 6;   ntsh = 11; dst = ws + 49152; li = idx - 49152; }
    else if (idx < 53248) { W = bW3; Ksrc = 128; Nsrc = 6;   ntsh = 11; dst = ws + 51200; li = idx - 51200; }
    else return;
    int e  = li & 7;
    int l  = (li >> 3) & 63;
    int KS = (ntsh == 10) ? 2 : 4;
    int ks = (li >> 9) & (KS - 1);
    int nt = li >> ntsh;
    int k  = ks * 32 + (l >> 4) * 8 + e;
    int n  = nt * 16 + (l & 15);
    float v = (k < Ksrc && n < Nsrc) ? W[k * Nsrc + n] : 0.0f;
    dst[li] = f2bf(v);
}

// ---------------- unary kernel (round-3 structure, unchanged) ----------------
__global__ __launch_bounds__(256, 3) void unary_kernel(
        const float* __restrict__ config, const float* __restrict__ action,
        const unsigned short* __restrict__ W1f, const float* __restrict__ b1,
        const unsigned short* __restrict__ W2f, const float* __restrict__ b2,
        const unsigned short* __restrict__ W3f, const float* __restrict__ b3,
        float* __restrict__ out) {
    __shared__ __align__(16) unsigned char smem[4 * 8192];
    const int tid = threadIdx.x;
    const int w = tid >> 6;
    const int l = tid & 63;
    const int g = l >> 4;
    const int c = l & 15;
    unsigned char* buf = smem + w * 8192;

    {
        const int rowL = l >> 1;
        const int kh   = l & 1;
        const int sw   = (rowL & 7) << 4;
        const int base = rowL * 128 + kh * 64;
        const int rg = blockIdx.x * 128 + w * 32 + rowL;
        const int b = rg >> 4;
        const int i = rg & 15;
        const float* cbr = config + b * 96 + i * 6;
        const float* ab  = action + b * 32;
        if (kh == 0) {
            float ov[6];
            { const float2 t0 = *(const float2*)(cbr);
              const float2 t1 = *(const float2*)(cbr + 2);
              const float2 t2 = *(const float2*)(cbr + 4);
              ov[0]=t0.x; ov[1]=t0.y; ov[2]=t1.x; ov[3]=t1.y; ov[4]=t2.x; ov[5]=t2.y; }
            float av[26];
            #pragma unroll
            for (int q = 0; q < 6; ++q) {
                const float4 t = *(const float4*)(ab + 4 * q);
                av[4*q]=t.x; av[4*q+1]=t.y; av[4*q+2]=t.z; av[4*q+3]=t.w;
            }
            { const float2 t = *(const float2*)(ab + 24); av[24]=t.x; av[25]=t.y; }
            #pragma unroll
            for (int ch = 0; ch < 4; ++ch) {
                float x[8];
                #pragma unroll
                for (int t8 = 0; t8 < 8; ++t8) {
                    const int k = ch * 8 + t8;
                    x[t8] = (k < 6) ? ov[k] : av[k - 6];
                }
                union { unsigned uu[4]; bf16x8 v; } U;
                U.uu[0] = pkbf(x[0], x[1]); U.uu[1] = pkbf(x[2], x[3]);
                U.uu[2] = pkbf(x[4], x[5]); U.uu[3] = pkbf(x[6], x[7]);
                *(bf16x8*)(buf + ((base + ch * 16) ^ sw)) = U.v;
            }
        } else {
            float av2[6];
            { const float2 t = *(const float2*)(ab + 26); av2[0]=t.x; av2[1]=t.y; }
            { const float4 t = *(const float4*)(ab + 28); av2[2]=t.x; av2[3]=t.y; av2[4]=t.z; av2[5]=t.w; }
            {
                union { unsigned uu[4]; bf16x8 v; } U;
                U.uu[0] = pkbf(av2[0], av2[1]); U.uu[1] = pkbf(av2[2], av2[3]);
                U.uu[2] = pkbf(av2[4], av2[5]); U.uu[3] = 0u;
                *(bf16x8*)(buf + ((base + 0) ^ sw)) = U.v;
            }
            const bf16x8 z = {0,0,0,0,0,0,0,0};
            *(bf16x8*)(buf + ((base + 16) ^ sw)) = z;
            *(bf16x8*)(buf + ((base + 32) ^ sw)) = z;
            *(bf16x8*)(buf + ((base + 48) ^ sw)) = z;
        }
    }
    __syncthreads();

    const f32x4 zero4 = {0.f, 0.f, 0.f, 0.f};

    bf16x8 xf[2][2];
    #pragma unroll
    for (int mt = 0; mt < 2; ++mt)
        #pragma unroll
        for (int ks = 0; ks < 2; ++ks) {
            const int row = mt * 16 + c;
            xf[mt][ks] = *(const bf16x8*)(buf + ((row * 128 + ks * 64 + g * 16) ^ ((c & 7) << 4)));
        }

    // GEMM1
    #pragma unroll
    for (int nh = 0; nh < 2; ++nh) {
        f32x4 acc[2][4];
        #pragma unroll
        for (int mt = 0; mt < 2; ++mt)
            #pragma unroll
            for (int ntl = 0; ntl < 4; ++ntl) acc[mt][ntl] = zero4;
        #pragma unroll
        for (int ntl = 0; ntl < 4; ++ntl) {
            const int nt = nh * 4 + ntl;
            #pragma unroll
            for (int ks = 0; ks < 2; ++ks) {
                const bf16x8 bfr = *(const bf16x8*)(W1f + ((nt * 2 + ks) * 64 + l) * 8);
                #pragma unroll
                for (int mt = 0; mt < 2; ++mt)
                    acc[mt][ntl] = __builtin_amdgcn_mfma_f32_16x16x32_bf16(xf[mt][ks], bfr, acc[mt][ntl], 0, 0, 0);
            }
        }
        #pragma unroll
        for (int ntl = 0; ntl < 4; ++ntl) {
            const int col = (nh * 4 + ntl) * 16 + c;
            const float bias = b1[col];
            #pragma unroll
            for (int mt = 0; mt < 2; ++mt)
                #pragma unroll
                for (int r = 0; r < 4; ++r) {
                    const int row = mt * 16 + g * 4 + r;
                    const float hv = fmaxf(acc[mt][ntl][r] + bias, 0.f);
                    *(unsigned short*)(buf + ((row * 256 + col * 2) ^ ((row & 7) << 4))) = f2bf(hv);
                }
        }
    }
    __syncthreads();

    bf16x8 hf[2][4];
    #pragma unroll
    for (int mt = 0; mt < 2; ++mt)
        #pragma unroll
        for (int ks = 0; ks < 4; ++ks) {
            const int row = mt * 16 + c;
            hf[mt][ks] = *(const bf16x8*)(buf + ((row * 256 + ks * 64 + g * 16) ^ ((c & 7) << 4)));
        }

    // GEMM2
    #pragma unroll
    for (int nh = 0; nh < 2; ++nh) {
        f32x4 acc[2][4];
        #pragma unroll
        for (int mt = 0; mt < 2; ++mt)
            #pragma unroll
            for (int ntl = 0; ntl < 4; ++ntl) acc[mt][ntl] = zero4;
        #pragma unroll
        for (int ntl = 0; ntl < 4; ++ntl) {
            const int nt = nh * 4 + ntl;
            #pragma unroll
            for (int ks = 0; ks < 4; ++ks) {
                const bf16x8 bfr = *(const bf16x8*)(W2f + ((nt * 4 + ks) * 64 + l) * 8);
                #pragma unroll
                for (int mt = 0; mt < 2; ++mt)
                    acc[mt][ntl] = __builtin_amdgcn_mfma_f32_16x16x32_bf16(hf[mt][ks], bfr, acc[mt][ntl], 0, 0, 0);
            }
        }
        #pragma unroll
        for (int ntl = 0; ntl < 4; ++ntl) {
            const int col = (nh * 4 + ntl) * 16 + c;
            const float bias = b2[col];
            #pragma unroll
            for (int mt = 0; mt < 2; ++mt)
                #pragma unroll
                for (int r = 0; r < 4; ++r) {
                    const int row = mt * 16 + g * 4 + r;
                    const float hv = fmaxf(acc[mt][ntl][r] + bias, 0.f);
                    *(unsigned short*)(buf + ((row * 256 + col * 2) ^ ((row & 7) << 4))) = f2bf(hv);
                }
        }
    }
    __syncthreads();

    bf16x8 h2f[2][4];
    #pragma unroll
    for (int mt = 0; mt < 2; ++mt)
        #pragma unroll
        for (int ks = 0; ks < 4; ++ks) {
            const int row = mt * 16 + c;
            h2f[mt][ks] = *(const bf16x8*)(buf + ((row * 256 + ks * 64 + g * 16) ^ ((c & 7) << 4)));
        }

    // GEMM3
    f32x4 acc3[2];
    acc3[0] = zero4; acc3[1] = zero4;
    #pragma unroll
    for (int ks = 0; ks < 4; ++ks) {
        const bf16x8 bfr = *(const bf16x8*)(W3f + (ks * 64 + l) * 8);
        #pragma unroll
        for (int mt = 0; mt < 2; ++mt)
            acc3[mt] = __builtin_amdgcn_mfma_f32_16x16x32_bf16(h2f[mt][ks], bfr, acc3[mt], 0, 0, 0);
    }

    const int rgbase = blockIdx.x * 128 + w * 32;
    const float b3v = (c < 6) ? b3[c] : 0.f;
    #pragma unroll
    for (int mt = 0; mt < 2; ++mt)
        #pragma unroll
        for (int r = 0; r < 4; ++r) {
            const int rg = rgbase + mt * 16 + g * 4 + r;
            const int b = rg >> 4, i = rg & 15;
            if (c < 6) {
                const int idx = b * 96 + i * 6 + c;
                out[idx] = acc3[mt][r] + b3v + config[idx];
            }
        }
}

// ---------------- binary kernel: chunked H1[i,j] = relu(P'[i] + Q[j]) ----------------
// grid 8192: b = blk>>1, h = blk&1. Block covers i in [8h, 8h+8), all j.
// PQ trimmed: rows 0-7 = P' for block-local i' (global i = 8h+i'), rows 8-23 = Q[j].
// Ts (phase 0-1) and Cks (chunk loop) share one 8KB union; total LDS 20.5KB.
__global__ __launch_bounds__(256, 5) void binary_kernel(
        const float* __restrict__ config, const float* __restrict__ action,
        const unsigned short* __restrict__ W1f, const float* __restrict__ b1,
        const unsigned short* __restrict__ W2f, const float* __restrict__ b2,
        const unsigned short* __restrict__ W3f, const float* __restrict__ b3,
        float* __restrict__ out) {
    __shared__ __align__(16) unsigned char PQs[12288];   // 24 rows x 128 f32, swizzled
    __shared__ __align__(16) unsigned char UNs[8192];    // Ts (32x64 bf16) then per-wave 2KB Cks

    unsigned char* Ts = UNs;
    const int tid = threadIdx.x;
    const int w = tid >> 6, l = tid & 63, g = l >> 4, c = l & 15;
    const int b = blockIdx.x >> 1, h = blockIdx.x & 1;
    const float* cb = config + b * 96;
    const float* ab = action + b * 32;
    const f32x4 zero4 = {0.f, 0.f, 0.f, 0.f};

    // ---- phase 0: build T. rows 0-7: [obj_{8h+p} | 0 | action | 0]; 8-15: zero; 16-31: [0 | obj_j | 0] ----
    {
        const int p  = tid >> 3;          // 0..31
        const int k0 = (tid & 7) * 8;     // 0..56
        union { unsigned short us[8]; bf16x8 v; } u;
        #pragma unroll
        for (int e = 0; e < 8; ++e) {
            const int k = k0 + e;
            float x = 0.f;
            if (p < 8) {
                if (k < 6) x = cb[(8 * h + p) * 6 + k];
                else if (k >= 12 && k < 44) x = ab[k - 12];
            } else if (p >= 16) {
                if (k >= 6 && k < 12) x = cb[(p - 16) * 6 + (k - 6)];
            }
            u.us[e] = f2bf(x);
        }
        *(bf16x8*)(Ts + ((p * 128 + k0 * 2) ^ ((p & 7) << 4))) = u.v;
    }
    __syncthreads();

    // ---- phase 1 (swapped): PQ^T = W1^T @ T^T; packed writes; skip dead P rows ----
    {
        bf16x8 tfr[2][2];
        #pragma unroll
        for (int nt = 0; nt < 2; ++nt)
            #pragma unroll
            for (int ks = 0; ks < 2; ++ks)
                tfr[nt][ks] = *(const bf16x8*)(Ts + (((c + 16 * nt) * 128 + 64 * ks + 16 * g) ^ ((c & 7) << 4)));
        f32x4 acc1[2][2];
        acc1[0][0] = zero4; acc1[0][1] = zero4; acc1[1][0] = zero4; acc1[1][1] = zero4;
        #pragma unroll
        for (int mt1 = 0; mt1 < 2; ++mt1) {
            #pragma unroll
            for (int ks = 0; ks < 2; ++ks) {
                const bf16x8 wfr = *(const bf16x8*)(W1f + (((2 * w + mt1) * 2 + ks) * 64 + l) * 8);
                acc1[mt1][0] = __builtin_amdgcn_mfma_f32_16x16x32_bf16(wfr, tfr[0][ks], acc1[mt1][0], 0, 0, 0);
                acc1[mt1][1] = __builtin_amdgcn_mfma_f32_16x16x32_bf16(wfr, tfr[1][ks], acc1[mt1][1], 0, 0, 0);
            }
        }
        #pragma unroll
        for (int mt1 = 0; mt1 < 2; ++mt1) {
            const f32x4 bv = *(const f32x4*)(b1 + 32 * w + 16 * mt1 + 4 * g);
            acc1[mt1][0] = acc1[mt1][0] + bv;   // bias only on P rows
            const int fb = (32 * w + 16 * mt1 + 4 * g) * 4;
            if (c < 8) {                        // P rows: block-local i' = c
                float2 v0; v0.x = acc1[mt1][0][0]; v0.y = acc1[mt1][0][1];
                float2 v1; v1.x = acc1[mt1][0][2]; v1.y = acc1[mt1][0][3];
                *(float2*)(PQs + ((c * 512 + fb)     ^ ((c & 7) << 4))) = v0;
                *(float2*)(PQs + ((c * 512 + fb + 8) ^ ((c & 7) << 4))) = v1;
            }
            {                                   // Q rows at 8 + j
                const int row = 8 + c;
                float2 v0; v0.x = acc1[mt1][1][0]; v0.y = acc1[mt1][1][1];
                float2 v1; v1.x = acc1[mt1][1][2]; v1.y = acc1[mt1][1][3];
                *(float2*)(PQs + ((row * 512 + fb)     ^ ((c & 7) << 4))) = v0;
                *(float2*)(PQs + ((row * 512 + fb + 8) ^ ((c & 7) << 4))) = v1;
            }
        }
    }
    __syncthreads();

    // ---- phase 2: H1 B-fragments in registers: relu(P'[i'] + Q[c]) ----
    const int i0 = h * 8 + 2 * w;               // global i base for this wave
    bf16x8 h1f[2][4];
    #pragma unroll
    for (int nt = 0; nt < 2; ++nt) {
        const int ip = 2 * w + nt;              // block-local P row
        #pragma unroll
        for (int ks = 0; ks < 4; ++ks) {
            const int kb = (32 * ks + 8 * g) * 4;
            const f32x4 p0 = *(const f32x4*)(PQs + ((ip * 512 + kb) ^ ((ip & 7) << 4)));
            const f32x4 p1 = *(const f32x4*)(PQs + ((ip * 512 + kb + 16) ^ ((ip & 7) << 4)));
            const f32x4 q0 = *(const f32x4*)(PQs + (((8 + c) * 512 + kb) ^ ((c & 7) << 4)));
            const f32x4 q1 = *(const f32x4*)(PQs + (((8 + c) * 512 + kb + 16) ^ ((c & 7) << 4)));
            union { unsigned u[4]; bf16x8 v; } un;
            un.u[0] = pkbf(fmaxf(p0[0] + q0[0], 0.f), fmaxf(p0[1] + q0[1], 0.f));
            un.u[1] = pkbf(fmaxf(p0[2] + q0[2], 0.f), fmaxf(p0[3] + q0[3], 0.f));
            un.u[2] = pkbf(fmaxf(p1[0] + q1[0], 0.f), fmaxf(p1[1] + q1[1], 0.f));
            un.u[3] = pkbf(fmaxf(p1[2] + q1[2], 0.f), fmaxf(p1[3] + q1[3], 0.f));
            h1f[nt][ks] = un.v;
        }
    }

    // ---- phases 3-5 fused, kappa-chunked: GEMM2(swapped) -> pack -> 2KB LDS -> GEMM3 ----
    unsigned char* Ck = UNs + w * 2048;
    f32x4 acc3[2];
    acc3[0] = zero4; acc3[1] = zero4;
    #pragma unroll 1
    for (int ks = 0; ks < 4; ++ks) {
        f32x4 a2[2][2];
        a2[0][0] = zero4; a2[0][1] = zero4; a2[1][0] = zero4; a2[1][1] = zero4;
        #pragma unroll
        for (int ksp = 0; ksp < 4; ++ksp) {
            #pragma unroll
            for (int mt1 = 0; mt1 < 2; ++mt1) {
                const bf16x8 wf = *(const bf16x8*)(W2f + (((2 * ks + mt1) * 4 + ksp) * 64 + l) * 8);
                a2[mt1][0] = __builtin_amdgcn_mfma_f32_16x16x32_bf16(wf, h1f[0][ksp], a2[mt1][0], 0, 0, 0);
                a2[mt1][1] = __builtin_amdgcn_mfma_f32_16x16x32_bf16(wf, h1f[1][ksp], a2[mt1][1], 0, 0, 0);
            }
        }
        // pack (bias+relu) and write chunk (kappa-local = 16*mt1 + 4g + r)
        #pragma unroll
        for (int mt1 = 0; mt1 < 2; ++mt1) {
            const f32x4 bv = *(const f32x4*)(b2 + 32 * ks + 16 * mt1 + 4 * g);
            #pragma unroll
            for (int nt = 0; nt < 2; ++nt) {
                const int p = c + 16 * nt;
                uint2 pk2;
                pk2.x = pkbf(fmaxf(a2[mt1][nt][0] + bv[0], 0.f), fmaxf(a2[mt1][nt][1] + bv[1], 0.f));
                pk2.y = pkbf(fmaxf(a2[mt1][nt][2] + bv[2], 0.f), fmaxf(a2[mt1][nt][3] + bv[3], 0.f));
                *(uint2*)(Ck + ((p * 64 + 32 * mt1 + 8 * g) ^ (((p >> 1) & 3) << 4))) = pk2;
            }
        }
        // GEMM3 partial: A = H2 chunk, B = W3f[ks]
        const bf16x8 w3 = *(const bf16x8*)(W3f + (ks * 64 + l) * 8);
        #pragma unroll
        for (int nt = 0; nt < 2; ++nt) {
            const int p = c + 16 * nt;
            const bf16x8 ha = *(const bf16x8*)(Ck + ((p * 64 + 16 * g) ^ (((p >> 1) & 3) << 4)));
            acc3[nt] = __builtin_amdgcn_mfma_f32_16x16x32_bf16(ha, w3, acc3[nt], 0, 0, 0);
        }
    }

    // ---- phase 6: mask diagonal (j = 4g+r), sum over j, accumulate into out ----
    const float b3v = (c < 6) ? b3[c] : 0.f;
    #pragma unroll
    for (int nt = 0; nt < 2; ++nt) {
        const int i = i0 + nt;
        float s = 0.f;
        #pragma unroll
        for (int r = 0; r < 4; ++r) {
            const int j = 4 * g + r;
            if (j != i) s += acc3[nt][r] + b3v;
        }
        s += __shfl_xor(s, 16, 64);
        s += __shfl_xor(s, 32, 64);
        if (g == 0 && c < 6) out[b * 96 + i * 6 + c] += s;
    }
}

extern "C" void kernel_launch(void* const* d_in, const int* in_sizes, int n_in,
                              void* d_out, int out_size, void* d_ws, size_t ws_size,
                              hipStream_t stream) {
    const float* config = (const float*)d_in[0];
    const float* action = (const float*)d_in[1];
    const float* uW1 = (const float*)d_in[2];
    const float* ub1 = (const float*)d_in[3];
    const float* uW2 = (const float*)d_in[4];
    const float* ub2 = (const float*)d_in[5];
    const float* uW3 = (const float*)d_in[6];
    const float* ub3 = (const float*)d_in[7];
    const float* bW1 = (const float*)d_in[8];
    const float* bb1 = (const float*)d_in[9];
    const float* bW2 = (const float*)d_in[10];
    const float* bb2 = (const float*)d_in[11];
    const float* bW3 = (const float*)d_in[12];
    const float* bb3 = (const float*)d_in[13];
    float* out = (float*)d_out;

    unsigned short* ws   = (unsigned short*)d_ws;
    unsigned short* uW1f = ws;            // 8192 elems
    unsigned short* bW1f = ws + 8192;     // 8192
    unsigned short* uW2f = ws + 16384;    // 16384
    unsigned short* bW2f = ws + 32768;    // 16384
    unsigned short* uW3f = ws + 49152;    // 2048
    unsigned short* bW3f = ws + 51200;    // 2048

    prep_all<<<208, 256, 0, stream>>>(uW1, uW2, uW3, bW1, bW2, bW3, ws);
    // unary first: writes out = objs + u_out (every element exactly once)
    unary_kernel<<<512, 256, 0, stream>>>(config, action, uW1f, ub1, uW2f, ub2, uW3f, ub3, out);
    // binary second: out += b_sum (stream-ordered after unary)
    binary_kernel<<<8192, 256, 0, stream>>>(config, action, bW1f, bb1, bW2f, bb2, bW3f, bb3, out);
}

// Round 5
// 162.294 us; speedup vs baseline: 1.0124x; 1.0124x over previous
//
#include <hip/hip_runtime.h>

typedef short bf16x8 __attribute__((ext_vector_type(8)));
typedef float f32x4 __attribute__((ext_vector_type(4)));

__device__ __forceinline__ unsigned short f2bf(float f) {
    unsigned int u = __float_as_uint(f);
    unsigned int r = u + 0x7FFFu + ((u >> 16) & 1u);
    return (unsigned short)(r >> 16);
}

// pack two f32 -> one u32 of 2 bf16 (lo = a, hi = b)
__device__ __forceinline__ unsigned pkbf(float a, float b) {
    unsigned r;
    asm volatile("v_cvt_pk_bf16_f32 %0, %1, %2" : "=v"(r) : "v"(a), "v"(b));
    return r;
}

// ---------------- weight prep: f32 row-major -> bf16 fragment-major ----------------
// frag layout: idx = ((nt*KS + ks)*64 + lane)*8 + e  ->  W[k = ks*32 + (lane>>4)*8 + e][n = nt*16 + (lane&15)]
__global__ __launch_bounds__(256) void prep_all(
        const float* __restrict__ uW1, const float* __restrict__ uW2, const float* __restrict__ uW3,
        const float* __restrict__ bW1, const float* __restrict__ bW2, const float* __restrict__ bW3,
        unsigned short* __restrict__ ws) {
    int idx = blockIdx.x * 256 + threadIdx.x;
    const float* W; int Ksrc, Nsrc, ntsh; unsigned short* dst; int li;
    if (idx < 8192)       { W = uW1; Ksrc = 38;  Nsrc = 128; ntsh = 10; dst = ws;         li = idx; }
    else if (idx < 16384) { W = bW1; Ksrc = 44;  Nsrc = 128; ntsh = 10; dst = ws + 8192;  li = idx - 8192; }
    else if (idx < 32768) { W = uW2; Ksrc = 128; Nsrc = 128; ntsh = 11; dst = ws + 16384; li = idx - 16384; }
    else if (idx < 49152) { W = bW2; Ksrc = 128; Nsrc = 128; ntsh = 11; dst = ws + 32768; li = idx - 32768; }
    else if (idx < 51200) { W = uW3; Ksrc = 128; Nsrc = 6;   ntsh = 11; dst = ws + 49152; li = idx - 49152; }
    else if (idx < 53248) { W = bW3; Ksrc = 128; Nsrc = 6;   ntsh = 11; dst = ws + 51200; li = idx - 51200; }
    else return;
    int e  = li & 7;
    int l  = (li >> 3) & 63;
    int KS = (ntsh == 10) ? 2 : 4;
    int ks = (li >> 9) & (KS - 1);
    int nt = li >> ntsh;
    int k  = ks * 32 + (l >> 4) * 8 + e;
    int n  = nt * 16 + (l & 15);
    float v = (k < Ksrc && n < Nsrc) ? W[k * Nsrc + n] : 0.0f;
    dst[li] = f2bf(v);
}

// ---------------- unary kernel (unchanged, verified) ----------------
__global__ __launch_bounds__(256, 3) void unary_kernel(
        const float* __restrict__ config, const float* __restrict__ action,
        const unsigned short* __restrict__ W1f, const float* __restrict__ b1,
        const unsigned short* __restrict__ W2f, const float* __restrict__ b2,
        const unsigned short* __restrict__ W3f, const float* __restrict__ b3,
        float* __restrict__ out) {
    __shared__ __align__(16) unsigned char smem[4 * 8192];
    const int tid = threadIdx.x;
    const int w = tid >> 6;
    const int l = tid & 63;
    const int g = l >> 4;
    const int c = l & 15;
    unsigned char* buf = smem + w * 8192;

    {
        const int rowL = l >> 1;
        const int kh   = l & 1;
        const int sw   = (rowL & 7) << 4;
        const int base = rowL * 128 + kh * 64;
        const int rg = blockIdx.x * 128 + w * 32 + rowL;
        const int b = rg >> 4;
        const int i = rg & 15;
        const float* cbr = config + b * 96 + i * 6;
        const float* ab  = action + b * 32;
        if (kh == 0) {
            float ov[6];
            { const float2 t0 = *(const float2*)(cbr);
              const float2 t1 = *(const float2*)(cbr + 2);
              const float2 t2 = *(const float2*)(cbr + 4);
              ov[0]=t0.x; ov[1]=t0.y; ov[2]=t1.x; ov[3]=t1.y; ov[4]=t2.x; ov[5]=t2.y; }
            float av[26];
            #pragma unroll
            for (int q = 0; q < 6; ++q) {
                const float4 t = *(const float4*)(ab + 4 * q);
                av[4*q]=t.x; av[4*q+1]=t.y; av[4*q+2]=t.z; av[4*q+3]=t.w;
            }
            { const float2 t = *(const float2*)(ab + 24); av[24]=t.x; av[25]=t.y; }
            #pragma unroll
            for (int ch = 0; ch < 4; ++ch) {
                float x[8];
                #pragma unroll
                for (int t8 = 0; t8 < 8; ++t8) {
                    const int k = ch * 8 + t8;
                    x[t8] = (k < 6) ? ov[k] : av[k - 6];
                }
                union { unsigned uu[4]; bf16x8 v; } U;
                U.uu[0] = pkbf(x[0], x[1]); U.uu[1] = pkbf(x[2], x[3]);
                U.uu[2] = pkbf(x[4], x[5]); U.uu[3] = pkbf(x[6], x[7]);
                *(bf16x8*)(buf + ((base + ch * 16) ^ sw)) = U.v;
            }
        } else {
            float av2[6];
            { const float2 t = *(const float2*)(ab + 26); av2[0]=t.x; av2[1]=t.y; }
            { const float4 t = *(const float4*)(ab + 28); av2[2]=t.x; av2[3]=t.y; av2[4]=t.z; av2[5]=t.w; }
            {
                union { unsigned uu[4]; bf16x8 v; } U;
                U.uu[0] = pkbf(av2[0], av2[1]); U.uu[1] = pkbf(av2[2], av2[3]);
                U.uu[2] = pkbf(av2[4], av2[5]); U.uu[3] = 0u;
                *(bf16x8*)(buf + ((base + 0) ^ sw)) = U.v;
            }
            const bf16x8 z = {0,0,0,0,0,0,0,0};
            *(bf16x8*)(buf + ((base + 16) ^ sw)) = z;
            *(bf16x8*)(buf + ((base + 32) ^ sw)) = z;
            *(bf16x8*)(buf + ((base + 48) ^ sw)) = z;
        }
    }
    __syncthreads();

    const f32x4 zero4 = {0.f, 0.f, 0.f, 0.f};

    bf16x8 xf[2][2];
    #pragma unroll
    for (int mt = 0; mt < 2; ++mt)
        #pragma unroll
        for (int ks = 0; ks < 2; ++ks) {
            const int row = mt * 16 + c;
            xf[mt][ks] = *(const bf16x8*)(buf + ((row * 128 + ks * 64 + g * 16) ^ ((c & 7) << 4)));
        }

    // GEMM1
    #pragma unroll
    for (int nh = 0; nh < 2; ++nh) {
        f32x4 acc[2][4];
        #pragma unroll
        for (int mt = 0; mt < 2; ++mt)
            #pragma unroll
            for (int ntl = 0; ntl < 4; ++ntl) acc[mt][ntl] = zero4;
        #pragma unroll
        for (int ntl = 0; ntl < 4; ++ntl) {
            const int nt = nh * 4 + ntl;
            #pragma unroll
            for (int ks = 0; ks < 2; ++ks) {
                const bf16x8 bfr = *(const bf16x8*)(W1f + ((nt * 2 + ks) * 64 + l) * 8);
                #pragma unroll
                for (int mt = 0; mt < 2; ++mt)
                    acc[mt][ntl] = __builtin_amdgcn_mfma_f32_16x16x32_bf16(xf[mt][ks], bfr, acc[mt][ntl], 0, 0, 0);
            }
        }
        #pragma unroll
        for (int ntl = 0; ntl < 4; ++ntl) {
            const int col = (nh * 4 + ntl) * 16 + c;
            const float bias = b1[col];
            #pragma unroll
            for (int mt = 0; mt < 2; ++mt)
                #pragma unroll
                for (int r = 0; r < 4; ++r) {
                    const int row = mt * 16 + g * 4 + r;
                    const float hv = fmaxf(acc[mt][ntl][r] + bias, 0.f);
                    *(unsigned short*)(buf + ((row * 256 + col * 2) ^ ((row & 7) << 4))) = f2bf(hv);
                }
        }
    }
    __syncthreads();

    bf16x8 hf[2][4];
    #pragma unroll
    for (int mt = 0; mt < 2; ++mt)
        #pragma unroll
        for (int ks = 0; ks < 4; ++ks) {
            const int row = mt * 16 + c;
            hf[mt][ks] = *(const bf16x8*)(buf + ((row * 256 + ks * 64 + g * 16) ^ ((c & 7) << 4)));
        }

    // GEMM2
    #pragma unroll
    for (int nh = 0; nh < 2; ++nh) {
        f32x4 acc[2][4];
        #pragma unroll
        for (int mt = 0; mt < 2; ++mt)
            #pragma unroll
            for (int ntl = 0; ntl < 4; ++ntl) acc[mt][ntl] = zero4;
        #pragma unroll
        for (int ntl = 0; ntl < 4; ++ntl) {
            const int nt = nh * 4 + ntl;
            #pragma unroll
            for (int ks = 0; ks < 4; ++ks) {
                const bf16x8 bfr = *(const bf16x8*)(W2f + ((nt * 4 + ks) * 64 + l) * 8);
                #pragma unroll
                for (int mt = 0; mt < 2; ++mt)
                    acc[mt][ntl] = __builtin_amdgcn_mfma_f32_16x16x32_bf16(hf[mt][ks], bfr, acc[mt][ntl], 0, 0, 0);
            }
        }
        #pragma unroll
        for (int ntl = 0; ntl < 4; ++ntl) {
            const int col = (nh * 4 + ntl) * 16 + c;
            const float bias = b2[col];
            #pragma unroll
            for (int mt = 0; mt < 2; ++mt)
                #pragma unroll
                for (int r = 0; r < 4; ++r) {
                    const int row = mt * 16 + g * 4 + r;
                    const float hv = fmaxf(acc[mt][ntl][r] + bias, 0.f);
                    *(unsigned short*)(buf + ((row * 256 + col * 2) ^ ((row & 7) << 4))) = f2bf(hv);
                }
        }
    }
    __syncthreads();

    bf16x8 h2f[2][4];
    #pragma unroll
    for (int mt = 0; mt < 2; ++mt)
        #pragma unroll
        for (int ks = 0; ks < 4; ++ks) {
            const int row = mt * 16 + c;
            h2f[mt][ks] = *(const bf16x8*)(buf + ((row * 256 + ks * 64 + g * 16) ^ ((c & 7) << 4)));
        }

    // GEMM3
    f32x4 acc3[2];
    acc3[0] = zero4; acc3[1] = zero4;
    #pragma unroll
    for (int ks = 0; ks < 4; ++ks) {
        const bf16x8 bfr = *(const bf16x8*)(W3f + (ks * 64 + l) * 8);
        #pragma unroll
        for (int mt = 0; mt < 2; ++mt)
            acc3[mt] = __builtin_amdgcn_mfma_f32_16x16x32_bf16(h2f[mt][ks], bfr, acc3[mt], 0, 0, 0);
    }

    const int rgbase = blockIdx.x * 128 + w * 32;
    const float b3v = (c < 6) ? b3[c] : 0.f;
    #pragma unroll
    for (int mt = 0; mt < 2; ++mt)
        #pragma unroll
        for (int r = 0; r < 4; ++r) {
            const int rg = rgbase + mt * 16 + g * 4 + r;
            const int b = rg >> 4, i = rg & 15;
            if (c < 6) {
                const int idx = b * 96 + i * 6 + c;
                out[idx] = acc3[mt][r] + b3v + config[idx];
            }
        }
}

// ---------------- binary kernel v3: register T-frags, 1 barrier, unrolled chunks ----------------
// grid 8192: b = blk>>1, h = blk&1. Block covers i in [8h, 8h+8), all j.
// PQ: rows 0-7 = P' (block-local i'), rows 8-23 = Q[j]. No T staging in LDS.
__global__ __launch_bounds__(256, 4) void binary_kernel(
        const float* __restrict__ config, const float* __restrict__ action,
        const unsigned short* __restrict__ W1f, const float* __restrict__ b1,
        const unsigned short* __restrict__ W2f, const float* __restrict__ b2,
        const unsigned short* __restrict__ W3f, const float* __restrict__ b3,
        float* __restrict__ out) {
    __shared__ __align__(16) unsigned char PQs[12288];   // 24 rows x 128 f32, swizzled
    __shared__ __align__(16) unsigned char Cks[8192];    // per-wave 2KB H2 kappa-chunk

    const int tid = threadIdx.x;
    const int w = tid >> 6, l = tid & 63, g = l >> 4, c = l & 15;
    const int b = blockIdx.x >> 1, h = blockIdx.x & 1;
    const float* cb = config + b * 96;
    const float* ab = action + b * 32;
    const f32x4 zero4 = {0.f, 0.f, 0.f, 0.f};

    // ---- T-fragments in registers (element e -> k = 32*ks + 8*g + e) ----
    // tP0/tP1: P columns (row index c; c>=8 duplicates c&7, discarded at write).
    // tQ0: Q columns (row c). tfr[1][1] == 0 -> those MFMAs skipped.
    bf16x8 tP0, tP1, tQ0;
    {
        const bf16x8 z8 = {0,0,0,0,0,0,0,0};
        tP0 = z8; tP1 = z8; tQ0 = z8;
        union { unsigned u[4]; bf16x8 v; } U;
        if (g == 0) {
            const float* obp = cb + (8 * h + (c & 7)) * 6;
            const float2 a0 = *(const float2*)obp, a1 = *(const float2*)(obp + 2), a2 = *(const float2*)(obp + 4);
            U.u[0] = pkbf(a0.x, a0.y); U.u[1] = pkbf(a1.x, a1.y); U.u[2] = pkbf(a2.x, a2.y); U.u[3] = 0u;
            tP0 = U.v;                                   // k 0..5 = obj_i, k 6,7 = 0
            const float4 b0 = *(const float4*)(ab + 20), b1v = *(const float4*)(ab + 24);
            U.u[0] = pkbf(b0.x, b0.y); U.u[1] = pkbf(b0.z, b0.w);
            U.u[2] = pkbf(b1v.x, b1v.y); U.u[3] = pkbf(b1v.z, b1v.w);
            tP1 = U.v;                                   // k 32..39 = action[20..27]
            const float2 q0 = *(const float2*)(cb + c * 6);
            U.u[0] = 0u; U.u[1] = 0u; U.u[2] = 0u; U.u[3] = pkbf(q0.x, q0.y);
            tQ0 = U.v;                                   // k 6,7 = obj_j[0,1]
        } else if (g == 1) {
            const float4 b0 = *(const float4*)(ab + 0);
            U.u[0] = 0u; U.u[1] = 0u; U.u[2] = pkbf(b0.x, b0.y); U.u[3] = pkbf(b0.z, b0.w);
            tP0 = U.v;                                   // k 12..15 = action[0..3]
            const float4 b1v = *(const float4*)(ab + 28);
            U.u[0] = pkbf(b1v.x, b1v.y); U.u[1] = pkbf(b1v.z, b1v.w); U.u[2] = 0u; U.u[3] = 0u;
            tP1 = U.v;                                   // k 40..43 = action[28..31]
            const float* obq = cb + c * 6;
            const float2 q1 = *(const float2*)(obq + 2), q2 = *(const float2*)(obq + 4);
            U.u[0] = pkbf(q1.x, q1.y); U.u[1] = pkbf(q2.x, q2.y); U.u[2] = 0u; U.u[3] = 0u;
            tQ0 = U.v;                                   // k 8..11 = obj_j[2..5]
        } else if (g == 2) {
            const float4 b0 = *(const float4*)(ab + 4), b1v = *(const float4*)(ab + 8);
            U.u[0] = pkbf(b0.x, b0.y); U.u[1] = pkbf(b0.z, b0.w);
            U.u[2] = pkbf(b1v.x, b1v.y); U.u[3] = pkbf(b1v.z, b1v.w);
            tP0 = U.v;                                   // k 16..23 = action[4..11]
        } else {
            const float4 b0 = *(const float4*)(ab + 12), b1v = *(const float4*)(ab + 16);
            U.u[0] = pkbf(b0.x, b0.y); U.u[1] = pkbf(b0.z, b0.w);
            U.u[2] = pkbf(b1v.x, b1v.y); U.u[3] = pkbf(b1v.z, b1v.w);
            tP0 = U.v;                                   // k 24..31 = action[12..19]
        }
    }

    // ---- phase 1 (swapped): PQ^T = W1^T @ T^T; 6 MFMAs; packed writes ----
    {
        f32x4 acc1[2][2];
        acc1[0][0] = zero4; acc1[0][1] = zero4; acc1[1][0] = zero4; acc1[1][1] = zero4;
        #pragma unroll
        for (int mt1 = 0; mt1 < 2; ++mt1) {
            const bf16x8 wf0 = *(const bf16x8*)(W1f + (((2 * w + mt1) * 2 + 0) * 64 + l) * 8);
            const bf16x8 wf1 = *(const bf16x8*)(W1f + (((2 * w + mt1) * 2 + 1) * 64 + l) * 8);
            acc1[mt1][0] = __builtin_amdgcn_mfma_f32_16x16x32_bf16(wf0, tP0, acc1[mt1][0], 0, 0, 0);
            acc1[mt1][0] = __builtin_amdgcn_mfma_f32_16x16x32_bf16(wf1, tP1, acc1[mt1][0], 0, 0, 0);
            acc1[mt1][1] = __builtin_amdgcn_mfma_f32_16x16x32_bf16(wf0, tQ0, acc1[mt1][1], 0, 0, 0);
        }
        #pragma unroll
        for (int mt1 = 0; mt1 < 2; ++mt1) {
            const f32x4 bv = *(const f32x4*)(b1 + 32 * w + 16 * mt1 + 4 * g);
            acc1[mt1][0] = acc1[mt1][0] + bv;   // bias only on P rows
            const int fb = (32 * w + 16 * mt1 + 4 * g) * 4;
            if (c < 8) {                        // P rows: block-local i' = c
                float2 v0; v0.x = acc1[mt1][0][0]; v0.y = acc1[mt1][0][1];
                float2 v1; v1.x = acc1[mt1][0][2]; v1.y = acc1[mt1][0][3];
                *(float2*)(PQs + ((c * 512 + fb)     ^ ((c & 7) << 4))) = v0;
                *(float2*)(PQs + ((c * 512 + fb + 8) ^ ((c & 7) << 4))) = v1;
            }
            {                                   // Q rows at 8 + j
                const int row = 8 + c;
                float2 v0; v0.x = acc1[mt1][1][0]; v0.y = acc1[mt1][1][1];
                float2 v1; v1.x = acc1[mt1][1][2]; v1.y = acc1[mt1][1][3];
                *(float2*)(PQs + ((row * 512 + fb)     ^ ((c & 7) << 4))) = v0;
                *(float2*)(PQs + ((row * 512 + fb + 8) ^ ((c & 7) << 4))) = v1;
            }
        }
    }
    __syncthreads();

    // ---- phase 2: H1 B-fragments: relu(P'[i'] + Q[c]); Q hoisted out of nt loop ----
    const int i0 = h * 8 + 2 * w;               // global i base for this wave
    bf16x8 h1f[2][4];
    #pragma unroll
    for (int ks = 0; ks < 4; ++ks) {
        const int kb = (32 * ks + 8 * g) * 4;
        const f32x4 q0 = *(const f32x4*)(PQs + (((8 + c) * 512 + kb) ^ ((c & 7) << 4)));
        const f32x4 q1 = *(const f32x4*)(PQs + (((8 + c) * 512 + kb + 16) ^ ((c & 7) << 4)));
        #pragma unroll
        for (int nt = 0; nt < 2; ++nt) {
            const int ip = 2 * w + nt;          // block-local P row (broadcast read)
            const f32x4 p0 = *(const f32x4*)(PQs + ((ip * 512 + kb) ^ ((ip & 7) << 4)));
            const f32x4 p1 = *(const f32x4*)(PQs + ((ip * 512 + kb + 16) ^ ((ip & 7) << 4)));
            union { unsigned u[4]; bf16x8 v; } un;
            un.u[0] = pkbf(fmaxf(p0[0] + q0[0], 0.f), fmaxf(p0[1] + q0[1], 0.f));
            un.u[1] = pkbf(fmaxf(p0[2] + q0[2], 0.f), fmaxf(p0[3] + q0[3], 0.f));
            un.u[2] = pkbf(fmaxf(p1[0] + q1[0], 0.f), fmaxf(p1[1] + q1[1], 0.f));
            un.u[3] = pkbf(fmaxf(p1[2] + q1[2], 0.f), fmaxf(p1[3] + q1[3], 0.f));
            h1f[nt][ks] = un.v;
        }
    }

    // ---- phases 3-5 fused, kappa-chunked (fully unrolled): GEMM2 -> pack -> LDS -> GEMM3 ----
    unsigned char* Ck = Cks + w * 2048;
    f32x4 acc3[2];
    acc3[0] = zero4; acc3[1] = zero4;
    #pragma unroll
    for (int ks = 0; ks < 4; ++ks) {
        f32x4 a2[2][2];
        a2[0][0] = zero4; a2[0][1] = zero4; a2[1][0] = zero4; a2[1][1] = zero4;
        #pragma unroll
        for (int ksp = 0; ksp < 4; ++ksp) {
            #pragma unroll
            for (int mt1 = 0; mt1 < 2; ++mt1) {
                const bf16x8 wf = *(const bf16x8*)(W2f + (((2 * ks + mt1) * 4 + ksp) * 64 + l) * 8);
                a2[mt1][0] = __builtin_amdgcn_mfma_f32_16x16x32_bf16(wf, h1f[0][ksp], a2[mt1][0], 0, 0, 0);
                a2[mt1][1] = __builtin_amdgcn_mfma_f32_16x16x32_bf16(wf, h1f[1][ksp], a2[mt1][1], 0, 0, 0);
            }
        }
        // pack (bias+relu) and write chunk; swizzle (p&7)<<4 -> conflict-free b128 reads
        #pragma unroll
        for (int mt1 = 0; mt1 < 2; ++mt1) {
            const f32x4 bv = *(const f32x4*)(b2 + 32 * ks + 16 * mt1 + 4 * g);
            #pragma unroll
            for (int nt = 0; nt < 2; ++nt) {
                const int p = c + 16 * nt;
                uint2 pk2;
                pk2.x = pkbf(fmaxf(a2[mt1][nt][0] + bv[0], 0.f), fmaxf(a2[mt1][nt][1] + bv[1], 0.f));
                pk2.y = pkbf(fmaxf(a2[mt1][nt][2] + bv[2], 0.f), fmaxf(a2[mt1][nt][3] + bv[3], 0.f));
                *(uint2*)(Ck + ((p * 64 + 32 * mt1 + 8 * g) ^ ((p & 7) << 4))) = pk2;
            }
        }
        // GEMM3 partial: A = H2 chunk, B = W3f[ks]
        const bf16x8 w3 = *(const bf16x8*)(W3f + (ks * 64 + l) * 8);
        #pragma unroll
        for (int nt = 0; nt < 2; ++nt) {
            const int p = c + 16 * nt;
            const bf16x8 ha = *(const bf16x8*)(Ck + ((p * 64 + 16 * g) ^ ((p & 7) << 4)));
            acc3[nt] = __builtin_amdgcn_mfma_f32_16x16x32_bf16(ha, w3, acc3[nt], 0, 0, 0);
        }
    }

    // ---- phase 6: mask diagonal (j = 4g+r), sum over j, accumulate into out ----
    const float b3v = (c < 6) ? b3[c] : 0.f;
    #pragma unroll
    for (int nt = 0; nt < 2; ++nt) {
        const int i = i0 + nt;
        float s = 0.f;
        #pragma unroll
        for (int r = 0; r < 4; ++r) {
            const int j = 4 * g + r;
            if (j != i) s += acc3[nt][r] + b3v;
        }
        s += __shfl_xor(s, 16, 64);
        s += __shfl_xor(s, 32, 64);
        if (g == 0 && c < 6) out[b * 96 + i * 6 + c] += s;
    }
}

extern "C" void kernel_launch(void* const* d_in, const int* in_sizes, int n_in,
                              void* d_out, int out_size, void* d_ws, size_t ws_size,
                              hipStream_t stream) {
    const float* config = (const float*)d_in[0];
    const float* action = (const float*)d_in[1];
    const float* uW1 = (const float*)d_in[2];
    const float* ub1 = (const float*)d_in[3];
    const float* uW2 = (const float*)d_in[4];
    const float* ub2 = (const float*)d_in[5];
    const float* uW3 = (const float*)d_in[6];
    const float* ub3 = (const float*)d_in[7];
    const float* bW1 = (const float*)d_in[8];
    const float* bb1 = (const float*)d_in[9];
    const float* bW2 = (const float*)d_in[10];
    const float* bb2 = (const float*)d_in[11];
    const float* bW3 = (const float*)d_in[12];
    const float* bb3 = (const float*)d_in[13];
    float* out = (float*)d_out;

    unsigned short* ws   = (unsigned short*)d_ws;
    unsigned short* uW1f = ws;            // 8192 elems
    unsigned short* bW1f = ws + 8192;     // 8192
    unsigned short* uW2f = ws + 16384;    // 16384
    unsigned short* bW2f = ws + 32768;    // 16384
    unsigned short* uW3f = ws + 49152;    // 2048
    unsigned short* bW3f = ws + 51200;    // 2048

    prep_all<<<208, 256, 0, stream>>>(uW1, uW2, uW3, bW1, bW2, bW3, ws);
    // unary first: writes out = objs + u_out (every element exactly once)
    unary_kernel<<<512, 256, 0, stream>>>(config, action, uW1f, ub1, uW2f, ub2, uW3f, ub3, out);
    // binary second: out += b_sum (stream-ordered after unary)
    binary_kernel<<<8192, 256, 0, stream>>>(config, action, bW1f, bb1, bW2f, bb2, bW3f, bb3, out);
}

// Round 6
// 160.728 us; speedup vs baseline: 1.0223x; 1.0097x over previous
//
#include <hip/hip_runtime.h>

typedef short bf16x8 __attribute__((ext_vector_type(8)));
typedef float f32x4 __attribute__((ext_vector_type(4)));

__device__ __forceinline__ unsigned short f2bf(float f) {
    unsigned int u = __float_as_uint(f);
    unsigned int r = u + 0x7FFFu + ((u >> 16) & 1u);
    return (unsigned short)(r >> 16);
}

// pack two f32 -> one u32 of 2 bf16 (lo = a, hi = b)
__device__ __forceinline__ unsigned pkbf(float a, float b) {
    unsigned r;
    asm volatile("v_cvt_pk_bf16_f32 %0, %1, %2" : "=v"(r) : "v"(a), "v"(b));
    return r;
}

// ---------------- weight prep: f32 row-major -> bf16 fragment-major ----------------
// frag layout: idx = ((nt*KS + ks)*64 + lane)*8 + e  ->  W[k = ks*32 + (lane>>4)*8 + e][n = nt*16 + (lane&15)]
__global__ __launch_bounds__(256) void prep_all(
        const float* __restrict__ uW1, const float* __restrict__ uW2, const float* __restrict__ uW3,
        const float* __restrict__ bW1, const float* __restrict__ bW2, const float* __restrict__ bW3,
        unsigned short* __restrict__ ws) {
    int idx = blockIdx.x * 256 + threadIdx.x;
    const float* W; int Ksrc, Nsrc, ntsh; unsigned short* dst; int li;
    if (idx < 8192)       { W = uW1; Ksrc = 38;  Nsrc = 128; ntsh = 10; dst = ws;         li = idx; }
    else if (idx < 16384) { W = bW1; Ksrc = 44;  Nsrc = 128; ntsh = 10; dst = ws + 8192;  li = idx - 8192; }
    else if (idx < 32768) { W = uW2; Ksrc = 128; Nsrc = 128; ntsh = 11; dst = ws + 16384; li = idx - 16384; }
    else if (idx < 49152) { W = bW2; Ksrc = 128; Nsrc = 128; ntsh = 11; dst = ws + 32768; li = idx - 32768; }
    else if (idx < 51200) { W = uW3; Ksrc = 128; Nsrc = 6;   ntsh = 11; dst = ws + 49152; li = idx - 49152; }
    else if (idx < 53248) { W = bW3; Ksrc = 128; Nsrc = 6;   ntsh = 11; dst = ws + 51200; li = idx - 51200; }
    else return;
    int e  = li & 7;
    int l  = (li >> 3) & 63;
    int KS = (ntsh == 10) ? 2 : 4;
    int ks = (li >> 9) & (KS - 1);
    int nt = li >> ntsh;
    int k  = ks * 32 + (l >> 4) * 8 + e;
    int n  = nt * 16 + (l & 15);
    float v = (k < Ksrc && n < Nsrc) ? W[k * Nsrc + n] : 0.0f;
    dst[li] = f2bf(v);
}

// ---------------- unary kernel (unchanged, verified) ----------------
__global__ __launch_bounds__(256, 3) void unary_kernel(
        const float* __restrict__ config, const float* __restrict__ action,
        const unsigned short* __restrict__ W1f, const float* __restrict__ b1,
        const unsigned short* __restrict__ W2f, const float* __restrict__ b2,
        const unsigned short* __restrict__ W3f, const float* __restrict__ b3,
        float* __restrict__ out) {
    __shared__ __align__(16) unsigned char smem[4 * 8192];
    const int tid = threadIdx.x;
    const int w = tid >> 6;
    const int l = tid & 63;
    const int g = l >> 4;
    const int c = l & 15;
    unsigned char* buf = smem + w * 8192;

    {
        const int rowL = l >> 1;
        const int kh   = l & 1;
        const int sw   = (rowL & 7) << 4;
        const int base = rowL * 128 + kh * 64;
        const int rg = blockIdx.x * 128 + w * 32 + rowL;
        const int b = rg >> 4;
        const int i = rg & 15;
        const float* cbr = config + b * 96 + i * 6;
        const float* ab  = action + b * 32;
        if (kh == 0) {
            float ov[6];
            { const float2 t0 = *(const float2*)(cbr);
              const float2 t1 = *(const float2*)(cbr + 2);
              const float2 t2 = *(const float2*)(cbr + 4);
              ov[0]=t0.x; ov[1]=t0.y; ov[2]=t1.x; ov[3]=t1.y; ov[4]=t2.x; ov[5]=t2.y; }
            float av[26];
            #pragma unroll
            for (int q = 0; q < 6; ++q) {
                const float4 t = *(const float4*)(ab + 4 * q);
                av[4*q]=t.x; av[4*q+1]=t.y; av[4*q+2]=t.z; av[4*q+3]=t.w;
            }
            { const float2 t = *(const float2*)(ab + 24); av[24]=t.x; av[25]=t.y; }
            #pragma unroll
            for (int ch = 0; ch < 4; ++ch) {
                float x[8];
                #pragma unroll
                for (int t8 = 0; t8 < 8; ++t8) {
                    const int k = ch * 8 + t8;
                    x[t8] = (k < 6) ? ov[k] : av[k - 6];
                }
                union { unsigned uu[4]; bf16x8 v; } U;
                U.uu[0] = pkbf(x[0], x[1]); U.uu[1] = pkbf(x[2], x[3]);
                U.uu[2] = pkbf(x[4], x[5]); U.uu[3] = pkbf(x[6], x[7]);
                *(bf16x8*)(buf + ((base + ch * 16) ^ sw)) = U.v;
            }
        } else {
            float av2[6];
            { const float2 t = *(const float2*)(ab + 26); av2[0]=t.x; av2[1]=t.y; }
            { const float4 t = *(const float4*)(ab + 28); av2[2]=t.x; av2[3]=t.y; av2[4]=t.z; av2[5]=t.w; }
            {
                union { unsigned uu[4]; bf16x8 v; } U;
                U.uu[0] = pkbf(av2[0], av2[1]); U.uu[1] = pkbf(av2[2], av2[3]);
                U.uu[2] = pkbf(av2[4], av2[5]); U.uu[3] = 0u;
                *(bf16x8*)(buf + ((base + 0) ^ sw)) = U.v;
            }
            const bf16x8 z = {0,0,0,0,0,0,0,0};
            *(bf16x8*)(buf + ((base + 16) ^ sw)) = z;
            *(bf16x8*)(buf + ((base + 32) ^ sw)) = z;
            *(bf16x8*)(buf + ((base + 48) ^ sw)) = z;
        }
    }
    __syncthreads();

    const f32x4 zero4 = {0.f, 0.f, 0.f, 0.f};

    bf16x8 xf[2][2];
    #pragma unroll
    for (int mt = 0; mt < 2; ++mt)
        #pragma unroll
        for (int ks = 0; ks < 2; ++ks) {
            const int row = mt * 16 + c;
            xf[mt][ks] = *(const bf16x8*)(buf + ((row * 128 + ks * 64 + g * 16) ^ ((c & 7) << 4)));
        }

    // GEMM1
    #pragma unroll
    for (int nh = 0; nh < 2; ++nh) {
        f32x4 acc[2][4];
        #pragma unroll
        for (int mt = 0; mt < 2; ++mt)
            #pragma unroll
            for (int ntl = 0; ntl < 4; ++ntl) acc[mt][ntl] = zero4;
        #pragma unroll
        for (int ntl = 0; ntl < 4; ++ntl) {
            const int nt = nh * 4 + ntl;
            #pragma unroll
            for (int ks = 0; ks < 2; ++ks) {
                const bf16x8 bfr = *(const bf16x8*)(W1f + ((nt * 2 + ks) * 64 + l) * 8);
                #pragma unroll
                for (int mt = 0; mt < 2; ++mt)
                    acc[mt][ntl] = __builtin_amdgcn_mfma_f32_16x16x32_bf16(xf[mt][ks], bfr, acc[mt][ntl], 0, 0, 0);
            }
        }
        #pragma unroll
        for (int ntl = 0; ntl < 4; ++ntl) {
            const int col = (nh * 4 + ntl) * 16 + c;
            const float bias = b1[col];
            #pragma unroll
            for (int mt = 0; mt < 2; ++mt)
                #pragma unroll
                for (int r = 0; r < 4; ++r) {
                    const int row = mt * 16 + g * 4 + r;
                    const float hv = fmaxf(acc[mt][ntl][r] + bias, 0.f);
                    *(unsigned short*)(buf + ((row * 256 + col * 2) ^ ((row & 7) << 4))) = f2bf(hv);
                }
        }
    }
    __syncthreads();

    bf16x8 hf[2][4];
    #pragma unroll
    for (int mt = 0; mt < 2; ++mt)
        #pragma unroll
        for (int ks = 0; ks < 4; ++ks) {
            const int row = mt * 16 + c;
            hf[mt][ks] = *(const bf16x8*)(buf + ((row * 256 + ks * 64 + g * 16) ^ ((c & 7) << 4)));
        }

    // GEMM2
    #pragma unroll
    for (int nh = 0; nh < 2; ++nh) {
        f32x4 acc[2][4];
        #pragma unroll
        for (int mt = 0; mt < 2; ++mt)
            #pragma unroll
            for (int ntl = 0; ntl < 4; ++ntl) acc[mt][ntl] = zero4;
        #pragma unroll
        for (int ntl = 0; ntl < 4; ++ntl) {
            const int nt = nh * 4 + ntl;
            #pragma unroll
            for (int ks = 0; ks < 4; ++ks) {
                const bf16x8 bfr = *(const bf16x8*)(W2f + ((nt * 4 + ks) * 64 + l) * 8);
                #pragma unroll
                for (int mt = 0; mt < 2; ++mt)
                    acc[mt][ntl] = __builtin_amdgcn_mfma_f32_16x16x32_bf16(hf[mt][ks], bfr, acc[mt][ntl], 0, 0, 0);
            }
        }
        #pragma unroll
        for (int ntl = 0; ntl < 4; ++ntl) {
            const int col = (nh * 4 + ntl) * 16 + c;
            const float bias = b2[col];
            #pragma unroll
            for (int mt = 0; mt < 2; ++mt)
                #pragma unroll
                for (int r = 0; r < 4; ++r) {
                    const int row = mt * 16 + g * 4 + r;
                    const float hv = fmaxf(acc[mt][ntl][r] + bias, 0.f);
                    *(unsigned short*)(buf + ((row * 256 + col * 2) ^ ((row & 7) << 4))) = f2bf(hv);
                }
        }
    }
    __syncthreads();

    bf16x8 h2f[2][4];
    #pragma unroll
    for (int mt = 0; mt < 2; ++mt)
        #pragma unroll
        for (int ks = 0; ks < 4; ++ks) {
            const int row = mt * 16 + c;
            h2f[mt][ks] = *(const bf16x8*)(buf + ((row * 256 + ks * 64 + g * 16) ^ ((c & 7) << 4)));
        }

    // GEMM3
    f32x4 acc3[2];
    acc3[0] = zero4; acc3[1] = zero4;
    #pragma unroll
    for (int ks = 0; ks < 4; ++ks) {
        const bf16x8 bfr = *(const bf16x8*)(W3f + (ks * 64 + l) * 8);
        #pragma unroll
        for (int mt = 0; mt < 2; ++mt)
            acc3[mt] = __builtin_amdgcn_mfma_f32_16x16x32_bf16(h2f[mt][ks], bfr, acc3[mt], 0, 0, 0);
    }

    const int rgbase = blockIdx.x * 128 + w * 32;
    const float b3v = (c < 6) ? b3[c] : 0.f;
    #pragma unroll
    for (int mt = 0; mt < 2; ++mt)
        #pragma unroll
        for (int r = 0; r < 4; ++r) {
            const int rg = rgbase + mt * 16 + g * 4 + r;
            const int b = rg >> 4, i = rg & 15;
            if (c < 6) {
                const int idx = b * 96 + i * 6 + c;
                out[idx] = acc3[mt][r] + b3v + config[idx];
            }
        }
}

// ---------------- binary kernel v4: batched chunk loads, bias-in-acc, dbuf Ck ----------------
// grid 8192: b = blk>>1, h = blk&1. Block covers i in [8h, 8h+8), all j.
// PQ: rows 0-7 = P' (block-local i'), rows 8-23 = Q[j]. No T staging in LDS.
__global__ __launch_bounds__(256, 4) void binary_kernel(
        const float* __restrict__ config, const float* __restrict__ action,
        const unsigned short* __restrict__ W1f, const float* __restrict__ b1,
        const unsigned short* __restrict__ W2f, const float* __restrict__ b2,
        const unsigned short* __restrict__ W3f, const float* __restrict__ b3,
        float* __restrict__ out) {
    __shared__ __align__(16) unsigned char PQs[12288];   // 24 rows x 128 f32, swizzled
    __shared__ __align__(16) unsigned char Cks[16384];   // per-wave 2x2KB H2 kappa-chunk (double-buffered)

    const int tid = threadIdx.x;
    const int w = tid >> 6, l = tid & 63, g = l >> 4, c = l & 15;
    const int b = blockIdx.x >> 1, h = blockIdx.x & 1;
    const float* cb = config + b * 96;
    const float* ab = action + b * 32;
    const f32x4 zero4 = {0.f, 0.f, 0.f, 0.f};

    // ---- preload phase-1 weights + bias (overlaps T-build global loads) ----
    bf16x8 wf1[2][2];
    #pragma unroll
    for (int mt1 = 0; mt1 < 2; ++mt1)
        #pragma unroll
        for (int ksp = 0; ksp < 2; ++ksp)
            wf1[mt1][ksp] = *(const bf16x8*)(W1f + (((2 * w + mt1) * 2 + ksp) * 64 + l) * 8);
    f32x4 b1v[2];
    b1v[0] = *(const f32x4*)(b1 + 32 * w + 4 * g);
    b1v[1] = *(const f32x4*)(b1 + 32 * w + 16 + 4 * g);
    const float b3v = (c < 6) ? b3[c] : 0.f;

    // ---- T-fragments in registers (element e -> k = 32*ks + 8*g + e) ----
    bf16x8 tP0, tP1, tQ0;
    {
        const bf16x8 z8 = {0,0,0,0,0,0,0,0};
        tP0 = z8; tP1 = z8; tQ0 = z8;
        union { unsigned u[4]; bf16x8 v; } U;
        if (g == 0) {
            const float* obp = cb + (8 * h + (c & 7)) * 6;
            const float2 a0 = *(const float2*)obp, a1 = *(const float2*)(obp + 2), a2 = *(const float2*)(obp + 4);
            U.u[0] = pkbf(a0.x, a0.y); U.u[1] = pkbf(a1.x, a1.y); U.u[2] = pkbf(a2.x, a2.y); U.u[3] = 0u;
            tP0 = U.v;                                   // k 0..5 = obj_i, k 6,7 = 0
            const float4 b0 = *(const float4*)(ab + 20), b1q = *(const float4*)(ab + 24);
            U.u[0] = pkbf(b0.x, b0.y); U.u[1] = pkbf(b0.z, b0.w);
            U.u[2] = pkbf(b1q.x, b1q.y); U.u[3] = pkbf(b1q.z, b1q.w);
            tP1 = U.v;                                   // k 32..39 = action[20..27]
            const float2 q0 = *(const float2*)(cb + c * 6);
            U.u[0] = 0u; U.u[1] = 0u; U.u[2] = 0u; U.u[3] = pkbf(q0.x, q0.y);
            tQ0 = U.v;                                   // k 6,7 = obj_j[0,1]
        } else if (g == 1) {
            const float4 b0 = *(const float4*)(ab + 0);
            U.u[0] = 0u; U.u[1] = 0u; U.u[2] = pkbf(b0.x, b0.y); U.u[3] = pkbf(b0.z, b0.w);
            tP0 = U.v;                                   // k 12..15 = action[0..3]
            const float4 b1q = *(const float4*)(ab + 28);
            U.u[0] = pkbf(b1q.x, b1q.y); U.u[1] = pkbf(b1q.z, b1q.w); U.u[2] = 0u; U.u[3] = 0u;
            tP1 = U.v;                                   // k 40..43 = action[28..31]
            const float* obq = cb + c * 6;
            const float2 q1 = *(const float2*)(obq + 2), q2 = *(const float2*)(obq + 4);
            U.u[0] = pkbf(q1.x, q1.y); U.u[1] = pkbf(q2.x, q2.y); U.u[2] = 0u; U.u[3] = 0u;
            tQ0 = U.v;                                   // k 8..11 = obj_j[2..5]
        } else if (g == 2) {
            const float4 b0 = *(const float4*)(ab + 4), b1q = *(const float4*)(ab + 8);
            U.u[0] = pkbf(b0.x, b0.y); U.u[1] = pkbf(b0.z, b0.w);
            U.u[2] = pkbf(b1q.x, b1q.y); U.u[3] = pkbf(b1q.z, b1q.w);
            tP0 = U.v;                                   // k 16..23 = action[4..11]
        } else {
            const float4 b0 = *(const float4*)(ab + 12), b1q = *(const float4*)(ab + 16);
            U.u[0] = pkbf(b0.x, b0.y); U.u[1] = pkbf(b0.z, b0.w);
            U.u[2] = pkbf(b1q.x, b1q.y); U.u[3] = pkbf(b1q.z, b1q.w);
            tP0 = U.v;                                   // k 24..31 = action[12..19]
        }
    }

    // ---- phase 1 (swapped): PQ^T = W1^T @ T^T; bias via acc init; 6 MFMAs ----
    {
        f32x4 acc1[2][2];
        acc1[0][0] = b1v[0]; acc1[0][1] = zero4;   // P rows get bias, Q rows don't
        acc1[1][0] = b1v[1]; acc1[1][1] = zero4;
        #pragma unroll
        for (int mt1 = 0; mt1 < 2; ++mt1) {
            acc1[mt1][0] = __builtin_amdgcn_mfma_f32_16x16x32_bf16(wf1[mt1][0], tP0, acc1[mt1][0], 0, 0, 0);
            acc1[mt1][0] = __builtin_amdgcn_mfma_f32_16x16x32_bf16(wf1[mt1][1], tP1, acc1[mt1][0], 0, 0, 0);
            acc1[mt1][1] = __builtin_amdgcn_mfma_f32_16x16x32_bf16(wf1[mt1][0], tQ0, acc1[mt1][1], 0, 0, 0);
        }
        #pragma unroll
        for (int mt1 = 0; mt1 < 2; ++mt1) {
            const int fb = (32 * w + 16 * mt1 + 4 * g) * 4;
            if (c < 8) {                        // P rows: block-local i' = c
                float2 v0; v0.x = acc1[mt1][0][0]; v0.y = acc1[mt1][0][1];
                float2 v1; v1.x = acc1[mt1][0][2]; v1.y = acc1[mt1][0][3];
                *(float2*)(PQs + ((c * 512 + fb)     ^ ((c & 7) << 4))) = v0;
                *(float2*)(PQs + ((c * 512 + fb + 8) ^ ((c & 7) << 4))) = v1;
            }
            {                                   // Q rows at 8 + j
                const int row = 8 + c;
                float2 v0; v0.x = acc1[mt1][1][0]; v0.y = acc1[mt1][1][1];
                float2 v1; v1.x = acc1[mt1][1][2]; v1.y = acc1[mt1][1][3];
                *(float2*)(PQs + ((row * 512 + fb)     ^ ((c & 7) << 4))) = v0;
                *(float2*)(PQs + ((row * 512 + fb + 8) ^ ((c & 7) << 4))) = v1;
            }
        }
    }
    __syncthreads();

    // ---- phase 2: H1 B-fragments: relu(P'[i'] + Q[c]); Q hoisted out of nt loop ----
    const int i0 = h * 8 + 2 * w;               // global i base for this wave
    bf16x8 h1f[2][4];
    #pragma unroll
    for (int ks = 0; ks < 4; ++ks) {
        const int kb = (32 * ks + 8 * g) * 4;
        const f32x4 q0 = *(const f32x4*)(PQs + (((8 + c) * 512 + kb) ^ ((c & 7) << 4)));
        const f32x4 q1 = *(const f32x4*)(PQs + (((8 + c) * 512 + kb + 16) ^ ((c & 7) << 4)));
        #pragma unroll
        for (int nt = 0; nt < 2; ++nt) {
            const int ip = 2 * w + nt;          // block-local P row (broadcast read)
            const f32x4 p0 = *(const f32x4*)(PQs + ((ip * 512 + kb) ^ ((ip & 7) << 4)));
            const f32x4 p1 = *(const f32x4*)(PQs + ((ip * 512 + kb + 16) ^ ((ip & 7) << 4)));
            union { unsigned u[4]; bf16x8 v; } un;
            un.u[0] = pkbf(fmaxf(p0[0] + q0[0], 0.f), fmaxf(p0[1] + q0[1], 0.f));
            un.u[1] = pkbf(fmaxf(p0[2] + q0[2], 0.f), fmaxf(p0[3] + q0[3], 0.f));
            un.u[2] = pkbf(fmaxf(p1[0] + q1[0], 0.f), fmaxf(p1[1] + q1[1], 0.f));
            un.u[3] = pkbf(fmaxf(p1[2] + q1[2], 0.f), fmaxf(p1[3] + q1[3], 0.f));
            h1f[nt][ks] = un.v;
        }
    }

    // ---- phases 3-5 fused, kappa-chunked: batched loads -> GEMM2 -> pack -> dbuf LDS -> GEMM3 ----
    f32x4 acc3[2];
    acc3[0][0] = b3v; acc3[0][1] = b3v; acc3[0][2] = b3v; acc3[0][3] = b3v;
    acc3[1] = acc3[0];
    #pragma unroll
    for (int ks = 0; ks < 4; ++ks) {
        // --- issue ALL loads for this chunk, then pin them before the MFMAs ---
        bf16x8 wfa[8];
        #pragma unroll
        for (int q = 0; q < 8; ++q)   // q = mt1*4 + ksp
            wfa[q] = *(const bf16x8*)(W2f + (((2 * ks + (q >> 2)) * 4 + (q & 3)) * 64 + l) * 8);
        const bf16x8 w3 = *(const bf16x8*)(W3f + (ks * 64 + l) * 8);
        const f32x4 bv0 = *(const f32x4*)(b2 + 32 * ks + 4 * g);
        const f32x4 bv1 = *(const f32x4*)(b2 + 32 * ks + 16 + 4 * g);
        __builtin_amdgcn_sched_barrier(0);

        f32x4 a2[2][2];
        a2[0][0] = bv0; a2[0][1] = bv0;   // bias in accumulator init
        a2[1][0] = bv1; a2[1][1] = bv1;
        #pragma unroll
        for (int ksp = 0; ksp < 4; ++ksp) {
            #pragma unroll
            for (int mt1 = 0; mt1 < 2; ++mt1) {
                a2[mt1][0] = __builtin_amdgcn_mfma_f32_16x16x32_bf16(wfa[mt1 * 4 + ksp], h1f[0][ksp], a2[mt1][0], 0, 0, 0);
                a2[mt1][1] = __builtin_amdgcn_mfma_f32_16x16x32_bf16(wfa[mt1 * 4 + ksp], h1f[1][ksp], a2[mt1][1], 0, 0, 0);
            }
        }
        // pack (relu) and write chunk (double-buffered; swizzle (p&7)<<4 -> conflict-free b128 reads)
        unsigned char* Ck = Cks + w * 4096 + (ks & 1) * 2048;
        #pragma unroll
        for (int mt1 = 0; mt1 < 2; ++mt1) {
            #pragma unroll
            for (int nt = 0; nt < 2; ++nt) {
                const int p = c + 16 * nt;
                uint2 pk2;
                pk2.x = pkbf(fmaxf(a2[mt1][nt][0], 0.f), fmaxf(a2[mt1][nt][1], 0.f));
                pk2.y = pkbf(fmaxf(a2[mt1][nt][2], 0.f), fmaxf(a2[mt1][nt][3], 0.f));
                *(uint2*)(Ck + ((p * 64 + 32 * mt1 + 8 * g) ^ ((p & 7) << 4))) = pk2;
            }
        }
        // GEMM3 partial: A = H2 chunk, B = W3f[ks]
        #pragma unroll
        for (int nt = 0; nt < 2; ++nt) {
            const int p = c + 16 * nt;
            const bf16x8 ha = *(const bf16x8*)(Ck + ((p * 64 + 16 * g) ^ ((p & 7) << 4)));
            acc3[nt] = __builtin_amdgcn_mfma_f32_16x16x32_bf16(ha, w3, acc3[nt], 0, 0, 0);
        }
    }

    // ---- phase 6: mask diagonal (j = 4g+r), sum over j, accumulate into out ----
    #pragma unroll
    for (int nt = 0; nt < 2; ++nt) {
        const int i = i0 + nt;
        float s = 0.f;
        #pragma unroll
        for (int r = 0; r < 4; ++r) {
            const int j = 4 * g + r;
            if (j != i) s += acc3[nt][r];      // b3 already in accumulator
        }
        s += __shfl_xor(s, 16, 64);
        s += __shfl_xor(s, 32, 64);
        if (g == 0 && c < 6) out[b * 96 + i * 6 + c] += s;
    }
}

extern "C" void kernel_launch(void* const* d_in, const int* in_sizes, int n_in,
                              void* d_out, int out_size, void* d_ws, size_t ws_size,
                              hipStream_t stream) {
    const float* config = (const float*)d_in[0];
    const float* action = (const float*)d_in[1];
    const float* uW1 = (const float*)d_in[2];
    const float* ub1 = (const float*)d_in[3];
    const float* uW2 = (const float*)d_in[4];
    const float* ub2 = (const float*)d_in[5];
    const float* uW3 = (const float*)d_in[6];
    const float* ub3 = (const float*)d_in[7];
    const float* bW1 = (const float*)d_in[8];
    const float* bb1 = (const float*)d_in[9];
    const float* bW2 = (const float*)d_in[10];
    const float* bb2 = (const float*)d_in[11];
    const float* bW3 = (const float*)d_in[12];
    const float* bb3 = (const float*)d_in[13];
    float* out = (float*)d_out;

    unsigned short* ws   = (unsigned short*)d_ws;
    unsigned short* uW1f = ws;            // 8192 elems
    unsigned short* bW1f = ws + 8192;     // 8192
    unsigned short* uW2f = ws + 16384;    // 16384
    unsigned short* bW2f = ws + 32768;    // 16384
    unsigned short* uW3f = ws + 49152;    // 2048
    unsigned short* bW3f = ws + 51200;    // 2048

    prep_all<<<208, 256, 0, stream>>>(uW1, uW2, uW3, bW1, bW2, bW3, ws);
    // unary first: writes out = objs + u_out (every element exactly once)
    unary_kernel<<<512, 256, 0, stream>>>(config, action, uW1f, ub1, uW2f, ub2, uW3f, ub3, out);
    // binary second: out += b_sum (stream-ordered after unary)
    binary_kernel<<<8192, 256, 0, stream>>>(config, action, bW1f, bb1, bW2f, bb2, bW3f, bb3, out);
}